// Round 3
// baseline (158.218 us; speedup 1.0000x reference)
//
#include <hip/hip_runtime.h>
#include <stdint.h>

// Problem constants
#define BB 2
#define SS 2048
#define HH 1024
#define NH 16
#define HD 64

#define LOG2E 1.4426950408889634f
#define QSCALE (0.125f * LOG2E)   // folded into Q at GEMM epilogue

typedef short bfrag  __attribute__((ext_vector_type(8)));   // 8 x bf16 (4 VGPRs)
typedef short bfrag4 __attribute__((ext_vector_type(4)));   // 4 x bf16 (2 VGPRs)
typedef float f32x4  __attribute__((ext_vector_type(4)));

__device__ __forceinline__ short f2bf(float f) {
    union { float f; uint32_t u; } v; v.f = f;
    uint32_t r = (v.u + 0x7fffu + ((v.u >> 16) & 1u)) >> 16;
    return (short)r;
}

// pack two f32 -> one dword of bf16 (lo = a, hi = b)
__device__ __forceinline__ uint32_t pack_bf16(float a, float b) {
#if __has_builtin(__builtin_amdgcn_cvt_pk_bf16_f32)
    auto t = __builtin_amdgcn_cvt_pk_bf16_f32(a, b);   // RNE, single VALU op
    uint32_t u; __builtin_memcpy(&u, &t, 4);
    return u;
#else
    uint32_t ua = __float_as_uint(a) + 0x8000u;
    uint32_t ub = __float_as_uint(b) + 0x8000u;
    return __builtin_amdgcn_perm(ub, ua, 0x07060302u);
#endif
}

// fused fp32->bf16 conversion: hidden (1048576 f4) + Wq/Wk/Wv (262144 f4 each,
// into contiguous Wcat) + mask*LOG2E (1024 f4, fp32 out). grid 7172.
__global__ __launch_bounds__(256) void cvt_all(
    const float* __restrict__ X,  const float* __restrict__ Wq,
    const float* __restrict__ Wk, const float* __restrict__ Wv,
    const float* __restrict__ mask,
    short* __restrict__ Xb, short* __restrict__ Wcat,
    float* __restrict__ maskl)
{
    int i = blockIdx.x * 256 + threadIdx.x;
    if (i >= 1835008) {
        int off = i - 1835008;   // 0..1023
        float4 f = ((const float4*)mask)[off];
        f.x *= LOG2E; f.y *= LOG2E; f.z *= LOG2E; f.w *= LOG2E;
        ((float4*)maskl)[off] = f;
        return;
    }
    const float* src; short* dst; int off;
    if (i < 1048576)      { src = X;  dst = Xb;                 off = i; }
    else if (i < 1310720) { src = Wq; dst = Wcat;               off = i - 1048576; }
    else if (i < 1572864) { src = Wk; dst = Wcat + 1048576;     off = i - 1310720; }
    else                  { src = Wv; dst = Wcat + 2097152;     off = i - 1572864; }
    float4 f = ((const float4*)src)[off];
    short4 s;
    s.x = f2bf(f.x); s.y = f2bf(f.y); s.z = f2bf(f.z); s.w = f2bf(f.w);
    ((short4*)dst)[off] = s;
}

__device__ __forceinline__ void gload_lds16(const void* g, void* lds) {
    __builtin_amdgcn_global_load_lds(
        (__attribute__((address_space(1))) void*)(uintptr_t)g,
        (__attribute__((address_space(3))) void*)(uintptr_t)lds,
        16, 0, 0);
}

// Fused QKV GEMM (BK=64, 2-barrier K-loop, (256,3) — known-good config).
// C[m][n] = sum_k X[m][k] * Wcat[n][k] + bias, M=4096 N=3072 K=1024.
// n in [0,1024) -> Q (pre-scaled by QSCALE), [1024,2048) -> K,
// [2048,3072) -> V^T [bh][d][s] with k-PERMUTED s within each 64-block:
// pos(k) = (g*4+q)*8 + h*4 + j for k = 32g+16h+4q+j. This order is
// simultaneously the K=32 PV B-operand k-order (see attn).
__global__ __launch_bounds__(256, 3) void qkv_gemm(
    const short* __restrict__ X, const short* __restrict__ Wcat,
    const float* __restrict__ bq, const float* __restrict__ bk, const float* __restrict__ bv,
    short* __restrict__ Qo, short* __restrict__ Ko, short* __restrict__ Vo)
{
    // main loop: As = smem[0..8191], Bs = smem[8192..16383] (shorts)
    // epilogue: reused as T[128][136] (17408 shorts)
    __shared__ __align__(16) short smem[17408];

    const int tid  = threadIdx.x;
    const int wave = tid >> 6, lane = tid & 63;
    const int quad = lane >> 4, l15 = lane & 15;
    const int mTile = blockIdx.y * 128;
    const int nTile = blockIdx.x * 128;
    const int z = nTile >> 10;                 // 0=Q,1=K,2=V (block-uniform)
    const int nLocT = nTile & 1023;
    const float* bias = (z == 0) ? bq : (z == 1) ? bk : bv;

    f32x4 acc[4][4];
#pragma unroll
    for (int i = 0; i < 4; ++i)
#pragma unroll
        for (int j = 0; j < 4; ++j) acc[i][j] = (f32x4)0.0f;

    const int srow  = lane >> 3;   // 0..7
    const int c_lin = lane & 7;
    const int mBase = (wave >> 1) * 64;
    const int nBase = (wave & 1) * 64;

    for (int k0 = 0; k0 < 1024; k0 += 64) {
        __syncthreads();
#pragma unroll
        for (int i = 0; i < 4; ++i) {
            int row = i * 32 + wave * 8 + srow;
            int cg  = c_lin ^ (row & 7);
            gload_lds16(X + (size_t)(mTile + row) * 1024 + k0 + cg * 8,
                        (char*)smem + i * 4096 + wave * 1024);
            gload_lds16(Wcat + (size_t)(nTile + row) * 1024 + k0 + cg * 8,
                        (char*)smem + 16384 + i * 4096 + wave * 1024);
        }
        __syncthreads();

#pragma unroll
        for (int kt = 0; kt < 2; ++kt) {
            bfrag af[4], bf[4];
#pragma unroll
            for (int t = 0; t < 4; ++t) {
                int arow = mBase + t * 16 + l15;
                int aslot = (kt * 4 + quad) ^ (arow & 7);
                af[t] = *(const bfrag*)((const char*)smem + arow * 128 + aslot * 16);
                int brow = nBase + t * 16 + l15;
                int bslot = (kt * 4 + quad) ^ (brow & 7);
                bf[t] = *(const bfrag*)((const char*)smem + 16384 + brow * 128 + bslot * 16);
            }
#pragma unroll
            for (int mt = 0; mt < 4; ++mt)
#pragma unroll
                for (int ct = 0; ct < 4; ++ct)
                    acc[mt][ct] = __builtin_amdgcn_mfma_f32_16x16x32_bf16(
                        af[mt], bf[ct], acc[mt][ct], 0, 0, 0);
        }
    }

    __syncthreads();   // main-loop LDS reads complete before T overwrite
    const int b = mTile >> 11, sBase = mTile & 2047;

    if (z == 2) {
        // T[n-local][s-local], pitch 136 -> k-permuted coalesced V^T stores
#pragma unroll
        for (int mt = 0; mt < 4; ++mt)
#pragma unroll
            for (int ct = 0; ct < 4; ++ct)
#pragma unroll
                for (int r = 0; r < 4; ++r) {
                    int nl = nBase + ct * 16 + l15;
                    int sl = mBase + mt * 16 + quad * 4 + r;
                    smem[nl * 136 + sl] = f2bf(acc[mt][ct][r] + bias[nLocT + nl]);
                }
        __syncthreads();
#pragma unroll
        for (int p = 0; p < 8; ++p) {
            int nl = p * 16 + (tid >> 4);     // d-row 0..127
            int cg = tid & 15;                // 16B chunk within 128-s tile
            int blk = cg >> 3;                // which 64-s block
            int c2  = cg & 7;                 // chunk within block: g = c2>>2, q = c2&3
            int base = blk * 64 + (c2 >> 2) * 32 + (c2 & 3) * 4;   // h=0 source
            int2 lo = *(const int2*)(smem + nl * 136 + base);       // k = ..+0..3
            int2 hi = *(const int2*)(smem + nl * 136 + base + 16);  // k = ..+16..19
            int4 v; v.x = lo.x; v.y = lo.y; v.z = hi.x; v.w = hi.y;
            int ng = nLocT + nl, hh = ng >> 6, d = ng & 63;
            *(int4*)(Vo + ((size_t)(b * 16 + hh) * 64 + d) * 2048 + sBase + cg * 8) = v;
        }
    } else {
        short* Out = (z == 0) ? Qo : Ko;
        float scale = (z == 0) ? QSCALE : 1.0f;
        // T[s-local][n-local], pitch 136 -> coalesced [bh][s][d] stores
#pragma unroll
        for (int mt = 0; mt < 4; ++mt)
#pragma unroll
            for (int ct = 0; ct < 4; ++ct)
#pragma unroll
                for (int r = 0; r < 4; ++r) {
                    int ml = mBase + mt * 16 + quad * 4 + r;
                    int nl = nBase + ct * 16 + l15;
                    smem[ml * 136 + nl] = f2bf((acc[mt][ct][r] + bias[nLocT + nl]) * scale);
                }
        __syncthreads();
#pragma unroll
        for (int p = 0; p < 8; ++p) {
            int ml = p * 16 + (tid >> 4);
            int c  = tid & 15;
            bfrag v8 = *(const bfrag*)(smem + ml * 136 + c * 8);
            int s  = sBase + ml;
            int nl = nLocT + c * 8, hh = nl >> 6, d = nl & 63;
            *(bfrag*)(Out + (((size_t)(b * 16 + hh) << 11) + s) * 64 + d) = v8;
        }
    }
}

// Flash attention (no-max softmax, log2 domain; Q pre-scaled by 0.125*log2e).
// 32 Q-rows per wave (two 16-row halves sharing every K/V LDS read).
// CROSS-TILE SOFTWARE PIPELINE (T15): per 64-key tile t the wave runs
//   QK(t) -> [ PV(t-1) MFMAs  ||  exp(t) VALU ]
// so the softmax trans/VALU work hides under the PV MFMA cluster (they are
// mutually independent). K/V are TRIPLE-buffered (6 x 8KB = 48KB LDS) so
// V(t-1) stays valid while tile t+1 is staged -> still ONE __syncthreads
// per tile, and every implicit vmcnt(0) drain is of 1-full-tile-old loads.
// p-state ping-pongs through statically named pA/pB (no runtime indexing).
// 4-wave blocks of 128 Q rows; grid 512. XCD-affinity: 4 bh per XCD
// (K+V 2MB L2-resident). Mask folded into QK MFMA C-operand; P packed via
// v_cvt_pk_bf16_f32. One b128 V read == K=32 PV B-operand (k-permuted V).
__global__ __launch_bounds__(256, 2) void attn_kernel(
    const short* __restrict__ Qb, const short* __restrict__ Kb, const short* __restrict__ Vb,
    const float* __restrict__ maskl, float* __restrict__ out)
{
    __shared__ __align__(16) char smem[49152];
    // K tiles: buf c at c*8192 (c=0,1,2); V^T tiles: 24576 + c*8192.
    // Each tile 8KB: 64 rows x 128B, XOR-swizzled 16B chunks (slot ^ (row&7)).

    const int tid  = threadIdx.x;
    const int wave = tid >> 6, lane = tid & 63;
    const int quad = lane >> 4, l15 = lane & 15;

    // XCD-affinity remap of the 512-block launch
    const int id = blockIdx.x;
    const int slot = id >> 3;                            // 0..63
    const int bh = ((id & 7) << 2) | (slot & 3);         // 0..31, fixed per XCD
    const int qt = slot >> 2;                            // 0..15
    const int b  = bh >> 4, h = bh & 15;
    const int qBase = qt * 128 + wave * 32;

    // staging source byte offsets (wave handles chunks wave*128 + i*64 + lane)
    int ksrc[2], vsrc[2];
#pragma unroll
    for (int i = 0; i < 2; ++i) {
        int ci = wave * 128 + i * 64 + lane;
        int r = ci >> 3, c = ci & 7;
        int cs = (c ^ (r & 7)) * 16;
        ksrc[i] = r * 128  + cs;    // K source: row stride 64 shorts = 128B
        vsrc[i] = r * 4096 + cs;    // V^T source: row stride 2048 shorts = 4096B
    }
    const char* kBase = (const char*)(Kb + (size_t)bh * SS * HD);
    const char* vBase = (const char*)(Vb + (size_t)bh * HD * SS);
    const char* mSrc  = (const char*)(maskl + b * SS) + quad * 16;

    // Q fragments (MFMA B-operand): Q[qrow=hf*16+l15][k=quad*8+j], pre-scaled
    const short* Qp = Qb + ((size_t)bh * SS + qBase) * HD;
    bfrag qf[2][2];
#pragma unroll
    for (int hf = 0; hf < 2; ++hf)
#pragma unroll
        for (int kt = 0; kt < 2; ++kt)
            qf[hf][kt] = *(const bfrag*)(Qp + (size_t)(hf * 16 + l15) * HD + kt * 32 + quad * 8);

    // j-invariant LDS read offsets (within a tile)
    int kAddr[2];
#pragma unroll
    for (int kt = 0; kt < 2; ++kt)
        kAddr[kt] = l15 * 128 + (((kt * 4 + quad) ^ (l15 & 7)) * 16);
    int vAddr[2];
#pragma unroll
    for (int g = 0; g < 2; ++g)
        vAddr[g] = 24576 + l15 * 128 + (((g * 4 + quad) ^ (l15 & 7)) * 16);

    const f32x4 z4 = (f32x4)0.0f;
    const bfrag ones8 = {0x3F80, 0x3F80, 0x3F80, 0x3F80,
                         0x3F80, 0x3F80, 0x3F80, 0x3F80};  // bf16 1.0 x8

    f32x4 oacc[2][4], ol[2];
#pragma unroll
    for (int hf = 0; hf < 2; ++hf) {
        ol[hf] = z4;
#pragma unroll
        for (int dt = 0; dt < 4; ++dt) oacc[hf][dt] = z4;
    }

    // P ping-pong state (statically named; no runtime indexing)
    bfrag pA0[2], pA1[2], pB0[2], pB1[2];

    // prologue: stage tile 0 into buffer 0
#pragma unroll
    for (int i = 0; i < 2; ++i) {
        gload_lds16(kBase + ksrc[i], smem + wave * 2048 + i * 1024);
        gload_lds16(vBase + vsrc[i], smem + 24576 + wave * 2048 + i * 1024);
    }

// One 64-key tile. JN = tile index to stage (t+1), CB = t%3, NB = (t+1)%3,
// PB = (t-1)%3. PC*/PP* = cur/prev P fragments. Program order inside:
// stage-issue, QK(t), PV(t-1) [independent of exp(t)], exp(t) -> scheduler
// weaves exp into the PV MFMA shadow.
#define TILE_BODY(JN, CB, NB, PB, PC0, PC1, PP0, PP1, DOPV, DOSTAGE)           \
    {                                                                          \
        __syncthreads();                                                       \
        if (DOSTAGE) {                                                         \
            _Pragma("unroll")                                                  \
            for (int i = 0; i < 2; ++i) {                                      \
                gload_lds16(kBase + (size_t)(JN) * 8192 + ksrc[i],             \
                            smem + (NB) * 8192 + wave * 2048 + i * 1024);      \
                gload_lds16(vBase + (size_t)(JN) * 128 + vsrc[i],              \
                            smem + 24576 + (NB) * 8192 + wave * 2048 + i * 1024); \
            }                                                                  \
        }                                                                      \
        f32x4 mvl[4];                                                          \
        _Pragma("unroll")                                                      \
        for (int ct = 0; ct < 4; ++ct)                                         \
            mvl[ct] = *(const f32x4*)(mSrc + ct * 64);                         \
        mSrc += 256;                                                           \
        f32x4 s0[4], s1[4];                                                    \
        _Pragma("unroll")                                                      \
        for (int ct = 0; ct < 4; ++ct) {                                       \
            bfrag kf0 = *(const bfrag*)(smem + (CB) * 8192 + kAddr[0] + ct * 2048); \
            bfrag kf1 = *(const bfrag*)(smem + (CB) * 8192 + kAddr[1] + ct * 2048); \
            s0[ct] = __builtin_amdgcn_mfma_f32_16x16x32_bf16(kf0, qf[0][0], mvl[ct], 0, 0, 0); \
            s0[ct] = __builtin_amdgcn_mfma_f32_16x16x32_bf16(kf1, qf[0][1], s0[ct],  0, 0, 0); \
            s1[ct] = __builtin_amdgcn_mfma_f32_16x16x32_bf16(kf0, qf[1][0], mvl[ct], 0, 0, 0); \
            s1[ct] = __builtin_amdgcn_mfma_f32_16x16x32_bf16(kf1, qf[1][1], s1[ct],  0, 0, 0); \
        }                                                                      \
        if (DOPV) {                                                           \
            _Pragma("unroll")                                                  \
            for (int g = 0; g < 2; ++g) {                                      \
                _Pragma("unroll")                                              \
                for (int dt = 0; dt < 4; ++dt) {                               \
                    bfrag v = *(const bfrag*)(smem + (PB) * 8192 + vAddr[g] + dt * 2048); \
                    oacc[0][dt] = __builtin_amdgcn_mfma_f32_16x16x32_bf16(PP0[g], v, oacc[0][dt], 0, 0, 0); \
                    oacc[1][dt] = __builtin_amdgcn_mfma_f32_16x16x32_bf16(PP1[g], v, oacc[1][dt], 0, 0, 0); \
                }                                                              \
                ol[0] = __builtin_amdgcn_mfma_f32_16x16x32_bf16(PP0[g], ones8, ol[0], 0, 0, 0); \
                ol[1] = __builtin_amdgcn_mfma_f32_16x16x32_bf16(PP1[g], ones8, ol[1], 0, 0, 0); \
            }                                                                  \
        }                                                                      \
        _Pragma("unroll")                                                      \
        for (int g = 0; g < 2; ++g) {                                          \
            union { uint32_t u[4]; bfrag v; } cvt;                             \
            cvt.u[0] = pack_bf16(__builtin_amdgcn_exp2f(s0[2*g][0]),   __builtin_amdgcn_exp2f(s0[2*g][1]));   \
            cvt.u[1] = pack_bf16(__builtin_amdgcn_exp2f(s0[2*g][2]),   __builtin_amdgcn_exp2f(s0[2*g][3]));   \
            cvt.u[2] = pack_bf16(__builtin_amdgcn_exp2f(s0[2*g+1][0]), __builtin_amdgcn_exp2f(s0[2*g+1][1])); \
            cvt.u[3] = pack_bf16(__builtin_amdgcn_exp2f(s0[2*g+1][2]), __builtin_amdgcn_exp2f(s0[2*g+1][3])); \
            PC0[g] = cvt.v;                                                    \
            cvt.u[0] = pack_bf16(__builtin_amdgcn_exp2f(s1[2*g][0]),   __builtin_amdgcn_exp2f(s1[2*g][1]));   \
            cvt.u[1] = pack_bf16(__builtin_amdgcn_exp2f(s1[2*g][2]),   __builtin_amdgcn_exp2f(s1[2*g][3]));   \
            cvt.u[2] = pack_bf16(__builtin_amdgcn_exp2f(s1[2*g+1][0]), __builtin_amdgcn_exp2f(s1[2*g+1][1])); \
            cvt.u[3] = pack_bf16(__builtin_amdgcn_exp2f(s1[2*g+1][2]), __builtin_amdgcn_exp2f(s1[2*g+1][3])); \
            PC1[g] = cvt.v;                                                    \
        }                                                                      \
    }

    // t=0: stage tile1, QK(0) from buf0, no PV, produce pA
    TILE_BODY(1, 0, 1, 0, pA0, pA1, pA0, pA1, 0, 1)
    // t=1: stage tile2, QK(1) from buf1, PV(0) from Vbuf0/pA, produce pB
    TILE_BODY(2, 1, 2, 0, pB0, pB1, pA0, pA1, 1, 1)

    // t = 2..31 in groups of 6 (buffer %3 x p-parity period)
    for (int jj = 0; jj < 5; ++jj) {
        int t2 = 6 * jj + 2;
        TILE_BODY(t2 + 1, 2, 0, 1, pA0, pA1, pB0, pB1, 1, 1)        // t = 6jj+2
        TILE_BODY(t2 + 2, 0, 1, 2, pB0, pB1, pA0, pA1, 1, 1)        // t = 6jj+3
        TILE_BODY(t2 + 3, 1, 2, 0, pA0, pA1, pB0, pB1, 1, 1)        // t = 6jj+4
        TILE_BODY(t2 + 4, 2, 0, 1, pB0, pB1, pA0, pA1, 1, 1)        // t = 6jj+5
        TILE_BODY(t2 + 5, 0, 1, 2, pA0, pA1, pB0, pB1, 1, 1)        // t = 6jj+6
        TILE_BODY(t2 + 6, 1, 2, 0, pB0, pB1, pA0, pA1, 1, (jj < 4)) // t = 6jj+7
    }
#undef TILE_BODY

    // final PV(31): prev = pB, V in buffer 31%3 = 1
#pragma unroll
    for (int g = 0; g < 2; ++g) {
#pragma unroll
        for (int dt = 0; dt < 4; ++dt) {
            bfrag v = *(const bfrag*)(smem + 8192 + vAddr[g] + dt * 2048);
            oacc[0][dt] = __builtin_amdgcn_mfma_f32_16x16x32_bf16(pB0[g], v, oacc[0][dt], 0, 0, 0);
            oacc[1][dt] = __builtin_amdgcn_mfma_f32_16x16x32_bf16(pB1[g], v, oacc[1][dt], 0, 0, 0);
        }
        ol[0] = __builtin_amdgcn_mfma_f32_16x16x32_bf16(pB0[g], ones8, ol[0], 0, 0, 0);
        ol[1] = __builtin_amdgcn_mfma_f32_16x16x32_bf16(pB1[g], ones8, ol[1], 0, 0, 0);
    }

    // epilogue: out[b][qrow][h*64+d] fp32; O rows = quad*4+r, cols = l15 (+16*dt)
#pragma unroll
    for (int hf = 0; hf < 2; ++hf) {
#pragma unroll
        for (int r = 0; r < 4; ++r) {
            float linv = 1.0f / ol[hf][r];
            int qrow = qBase + hf * 16 + quad * 4 + r;
#pragma unroll
            for (int dt = 0; dt < 4; ++dt)
                out[((size_t)(b * SS + qrow)) * HH + h * 64 + dt * 16 + l15] =
                    oacc[hf][dt][r] * linv;
        }
    }
}

extern "C" void kernel_launch(void* const* d_in, const int* in_sizes, int n_in,
                              void* d_out, int out_size, void* d_ws, size_t ws_size,
                              hipStream_t stream) {
    const float* hs   = (const float*)d_in[0];
    const float* mask = (const float*)d_in[1];
    const float* Wq   = (const float*)d_in[2];
    const float* bq   = (const float*)d_in[3];
    const float* Wk   = (const float*)d_in[4];
    const float* bk   = (const float*)d_in[5];
    const float* Wv   = (const float*)d_in[6];
    const float* bv   = (const float*)d_in[7];
    float* out = (float*)d_out;

    char* ws = (char*)d_ws;
    short* Xb    = (short*)(ws);                      // [4096][1024] bf16, 8 MiB
    short* Wcat  = (short*)(ws + (8ull  << 20));      // [3072][1024] bf16, 6 MiB (Wq|Wk|Wv)
    short* Qb    = (short*)(ws + (14ull << 20));      // [bh][s][d] 8 MiB (pre-scaled)
    short* Kb    = (short*)(ws + (22ull << 20));      // [bh][s][d] 8 MiB
    short* Vb    = (short*)(ws + (30ull << 20));      // [bh][d][s-permuted] 8 MiB
    float* maskl = (float*)(ws + (38ull << 20));      // [B][S] fp32, 16 KiB

    cvt_all<<<7172, 256, 0, stream>>>(hs, Wq, Wk, Wv, mask, Xb, Wcat, maskl);

    qkv_gemm<<<dim3(24, 32), 256, 0, stream>>>(Xb, Wcat, bq, bk, bv, Qb, Kb, Vb);

    attn_kernel<<<512, 256, 0, stream>>>(Qb, Kb, Vb, maskl, out);
}

// Round 4
// 155.340 us; speedup vs baseline: 1.0185x; 1.0185x over previous
//
#include <hip/hip_runtime.h>
#include <stdint.h>

// Problem constants
#define BB 2
#define SS 2048
#define HH 1024
#define NH 16
#define HD 64

#define LOG2E 1.4426950408889634f
#define QSCALE (0.125f * LOG2E)   // folded into Q at GEMM epilogue

typedef short bfrag  __attribute__((ext_vector_type(8)));   // 8 x bf16 (4 VGPRs)
typedef short bfrag4 __attribute__((ext_vector_type(4)));   // 4 x bf16 (2 VGPRs)
typedef float f32x4  __attribute__((ext_vector_type(4)));

__device__ __forceinline__ short f2bf(float f) {
    union { float f; uint32_t u; } v; v.f = f;
    uint32_t r = (v.u + 0x7fffu + ((v.u >> 16) & 1u)) >> 16;
    return (short)r;
}

// pack two f32 -> one dword of bf16 (lo = a, hi = b)
__device__ __forceinline__ uint32_t pack_bf16(float a, float b) {
#if __has_builtin(__builtin_amdgcn_cvt_pk_bf16_f32)
    auto t = __builtin_amdgcn_cvt_pk_bf16_f32(a, b);   // RNE, single VALU op
    uint32_t u; __builtin_memcpy(&u, &t, 4);
    return u;
#else
    uint32_t ua = __float_as_uint(a) + 0x8000u;
    uint32_t ub = __float_as_uint(b) + 0x8000u;
    return __builtin_amdgcn_perm(ub, ua, 0x07060302u);
#endif
}

// fused fp32->bf16 conversion: hidden (1048576 f4) + Wq/Wk/Wv (262144 f4 each,
// into contiguous Wcat) + mask*LOG2E (1024 f4, fp32 out). grid 7172.
__global__ __launch_bounds__(256) void cvt_all(
    const float* __restrict__ X,  const float* __restrict__ Wq,
    const float* __restrict__ Wk, const float* __restrict__ Wv,
    const float* __restrict__ mask,
    short* __restrict__ Xb, short* __restrict__ Wcat,
    float* __restrict__ maskl)
{
    int i = blockIdx.x * 256 + threadIdx.x;
    if (i >= 1835008) {
        int off = i - 1835008;   // 0..1023
        float4 f = ((const float4*)mask)[off];
        f.x *= LOG2E; f.y *= LOG2E; f.z *= LOG2E; f.w *= LOG2E;
        ((float4*)maskl)[off] = f;
        return;
    }
    const float* src; short* dst; int off;
    if (i < 1048576)      { src = X;  dst = Xb;                 off = i; }
    else if (i < 1310720) { src = Wq; dst = Wcat;               off = i - 1048576; }
    else if (i < 1572864) { src = Wk; dst = Wcat + 1048576;     off = i - 1310720; }
    else                  { src = Wv; dst = Wcat + 2097152;     off = i - 1572864; }
    float4 f = ((const float4*)src)[off];
    short4 s;
    s.x = f2bf(f.x); s.y = f2bf(f.y); s.z = f2bf(f.z); s.w = f2bf(f.w);
    ((short4*)dst)[off] = s;
}

__device__ __forceinline__ void gload_lds16(const void* g, void* lds) {
    __builtin_amdgcn_global_load_lds(
        (__attribute__((address_space(1))) void*)(uintptr_t)g,
        (__attribute__((address_space(3))) void*)(uintptr_t)lds,
        16, 0, 0);
}

// Fused QKV GEMM (BK=64, 2-barrier K-loop, (256,3) — known-good config).
// C[m][n] = sum_k X[m][k] * Wcat[n][k] + bias, M=4096 N=3072 K=1024.
// n in [0,1024) -> Q (pre-scaled by QSCALE), [1024,2048) -> K,
// [2048,3072) -> V^T [bh][d][s] with k-PERMUTED s within each 64-block:
// pos(k) = (g*4+q)*8 + h*4 + j for k = 32g+16h+4q+j. This order is
// simultaneously the K=32 PV B-operand k-order (see attn).
__global__ __launch_bounds__(256, 3) void qkv_gemm(
    const short* __restrict__ X, const short* __restrict__ Wcat,
    const float* __restrict__ bq, const float* __restrict__ bk, const float* __restrict__ bv,
    short* __restrict__ Qo, short* __restrict__ Ko, short* __restrict__ Vo)
{
    // main loop: As = smem[0..8191], Bs = smem[8192..16383] (shorts)
    // epilogue: reused as T[128][136] (17408 shorts)
    __shared__ __align__(16) short smem[17408];

    const int tid  = threadIdx.x;
    const int wave = tid >> 6, lane = tid & 63;
    const int quad = lane >> 4, l15 = lane & 15;
    const int mTile = blockIdx.y * 128;
    const int nTile = blockIdx.x * 128;
    const int z = nTile >> 10;                 // 0=Q,1=K,2=V (block-uniform)
    const int nLocT = nTile & 1023;
    const float* bias = (z == 0) ? bq : (z == 1) ? bk : bv;

    f32x4 acc[4][4];
#pragma unroll
    for (int i = 0; i < 4; ++i)
#pragma unroll
        for (int j = 0; j < 4; ++j) acc[i][j] = (f32x4)0.0f;

    const int srow  = lane >> 3;   // 0..7
    const int c_lin = lane & 7;
    const int mBase = (wave >> 1) * 64;
    const int nBase = (wave & 1) * 64;

    for (int k0 = 0; k0 < 1024; k0 += 64) {
        __syncthreads();
#pragma unroll
        for (int i = 0; i < 4; ++i) {
            int row = i * 32 + wave * 8 + srow;
            int cg  = c_lin ^ (row & 7);
            gload_lds16(X + (size_t)(mTile + row) * 1024 + k0 + cg * 8,
                        (char*)smem + i * 4096 + wave * 1024);
            gload_lds16(Wcat + (size_t)(nTile + row) * 1024 + k0 + cg * 8,
                        (char*)smem + 16384 + i * 4096 + wave * 1024);
        }
        __syncthreads();

#pragma unroll
        for (int kt = 0; kt < 2; ++kt) {
            bfrag af[4], bf[4];
#pragma unroll
            for (int t = 0; t < 4; ++t) {
                int arow = mBase + t * 16 + l15;
                int aslot = (kt * 4 + quad) ^ (arow & 7);
                af[t] = *(const bfrag*)((const char*)smem + arow * 128 + aslot * 16);
                int brow = nBase + t * 16 + l15;
                int bslot = (kt * 4 + quad) ^ (brow & 7);
                bf[t] = *(const bfrag*)((const char*)smem + 16384 + brow * 128 + bslot * 16);
            }
#pragma unroll
            for (int mt = 0; mt < 4; ++mt)
#pragma unroll
                for (int ct = 0; ct < 4; ++ct)
                    acc[mt][ct] = __builtin_amdgcn_mfma_f32_16x16x32_bf16(
                        af[mt], bf[ct], acc[mt][ct], 0, 0, 0);
        }
    }

    __syncthreads();   // main-loop LDS reads complete before T overwrite
    const int b = mTile >> 11, sBase = mTile & 2047;

    if (z == 2) {
        // T[n-local][s-local], pitch 136 -> k-permuted coalesced V^T stores
#pragma unroll
        for (int mt = 0; mt < 4; ++mt)
#pragma unroll
            for (int ct = 0; ct < 4; ++ct)
#pragma unroll
                for (int r = 0; r < 4; ++r) {
                    int nl = nBase + ct * 16 + l15;
                    int sl = mBase + mt * 16 + quad * 4 + r;
                    smem[nl * 136 + sl] = f2bf(acc[mt][ct][r] + bias[nLocT + nl]);
                }
        __syncthreads();
#pragma unroll
        for (int p = 0; p < 8; ++p) {
            int nl = p * 16 + (tid >> 4);     // d-row 0..127
            int cg = tid & 15;                // 16B chunk within 128-s tile
            int blk = cg >> 3;                // which 64-s block
            int c2  = cg & 7;                 // chunk within block: g = c2>>2, q = c2&3
            int base = blk * 64 + (c2 >> 2) * 32 + (c2 & 3) * 4;   // h=0 source
            int2 lo = *(const int2*)(smem + nl * 136 + base);       // k = ..+0..3
            int2 hi = *(const int2*)(smem + nl * 136 + base + 16);  // k = ..+16..19
            int4 v; v.x = lo.x; v.y = lo.y; v.z = hi.x; v.w = hi.y;
            int ng = nLocT + nl, hh = ng >> 6, d = ng & 63;
            *(int4*)(Vo + ((size_t)(b * 16 + hh) * 64 + d) * 2048 + sBase + cg * 8) = v;
        }
    } else {
        short* Out = (z == 0) ? Qo : Ko;
        float scale = (z == 0) ? QSCALE : 1.0f;
        // T[s-local][n-local], pitch 136 -> coalesced [bh][s][d] stores
#pragma unroll
        for (int mt = 0; mt < 4; ++mt)
#pragma unroll
            for (int ct = 0; ct < 4; ++ct)
#pragma unroll
                for (int r = 0; r < 4; ++r) {
                    int ml = mBase + mt * 16 + quad * 4 + r;
                    int nl = nBase + ct * 16 + l15;
                    smem[ml * 136 + nl] = f2bf((acc[mt][ct][r] + bias[nLocT + nl]) * scale);
                }
        __syncthreads();
#pragma unroll
        for (int p = 0; p < 8; ++p) {
            int ml = p * 16 + (tid >> 4);
            int c  = tid & 15;
            bfrag v8 = *(const bfrag*)(smem + ml * 136 + c * 8);
            int s  = sBase + ml;
            int nl = nLocT + c * 8, hh = nl >> 6, d = nl & 63;
            *(bfrag*)(Out + (((size_t)(b * 16 + hh) << 11) + s) * 64 + d) = v8;
        }
    }
}

// Flash attention (no-max softmax, log2 domain; Q pre-scaled by 0.125*log2e).
// 32 Q-rows per wave (two 16-row halves sharing every K/V LDS read).
// Bc=128 per astep: TWO independent 64-key sub-tiles per barrier.
// KEY FIX (r4): the mask is staged into LDS ONCE in the prologue and read
// via ds_read_b128 in the loop. Previously the mask was a per-tile GLOBAL
// load issued AFTER the staging global_load_lds in the VMEM FIFO; since
// vmcnt is FIFO-ordered, waiting for the mask (C-operand of the first QK
// MFMA) forced vmcnt(0) — draining the next-tile staging loads at the START
// of every tile's compute and serializing staging latency with compute.
// With the mask in LDS the tile body has NO vmem-dependent consumer; the
// only staging drain is the pre-barrier vmcnt(0), covered by a full astep
// of compute. LDS: 2 x 32KB K/V double-buffer + 8KB mask = 72KB, 2 blk/CU.
// K LDS tile [128 keys][64 d] (128B rows, chunk ^ (row&7) swizzle);
// V^T LDS tile [64 d][128 k-permuted keys] (256B rows, chunk ^ (row&15)
// swizzle). One b128 V read == K=32 PV B-operand (k-permuted V store).
// 4-wave blocks of 128 Q rows; grid 512. XCD-affinity: 4 bh per XCD
// (K+V 2MB L2-resident). P packed via v_cvt_pk_bf16_f32.
__global__ __launch_bounds__(256, 2) void attn_kernel(
    const short* __restrict__ Qb, const short* __restrict__ Kb, const short* __restrict__ Vb,
    const float* __restrict__ maskl, float* __restrict__ out)
{
    __shared__ __align__(16) char smem[73728];
    // buffers: stage c (c=0,1) at c*32768: K tile @+0 (16KB), V^T @+16384 (16KB)
    // mask: 8KB fp32 (this block's b row, *LOG2E) at 65536, linear

    const int tid  = threadIdx.x;
    const int wave = tid >> 6, lane = tid & 63;
    const int quad = lane >> 4, l15 = lane & 15;

    // XCD-affinity remap of the 512-block launch
    const int id = blockIdx.x;
    const int slot = id >> 3;                            // 0..63
    const int bh = ((id & 7) << 2) | (slot & 3);         // 0..31, fixed per XCD
    const int qt = slot >> 2;                            // 0..15
    const int b  = bh >> 4, h = bh & 15;
    const int qBase = qt * 128 + wave * 32;

    // staging source byte offsets (wave handles chunks wave*256 + i*64 + lane)
    int ksrc[4], vsrc[4];
#pragma unroll
    for (int i = 0; i < 4; ++i) {
        int ci = wave * 256 + i * 64 + lane;
        int kr = ci >> 3, kc = ci & 7;
        ksrc[i] = kr * 128 + ((kc ^ (kr & 7)) * 16);     // K rows: 128B stride
        int vr = ci >> 4, vc = ci & 15;
        vsrc[i] = vr * 4096 + ((vc ^ (vr & 15)) * 16);   // V^T rows: 4096B stride, 256B used
    }
    const char* kBase = (const char*)(Kb + (size_t)bh * SS * HD);
    const char* vBase = (const char*)(Vb + (size_t)bh * HD * SS);

    // Q fragments (MFMA B-operand): Q[qrow=hf*16+l15][k=quad*8+j], pre-scaled
    const short* Qp = Qb + ((size_t)bh * SS + qBase) * HD;
    bfrag qf[2][2];
#pragma unroll
    for (int hf = 0; hf < 2; ++hf)
#pragma unroll
        for (int kt = 0; kt < 2; ++kt)
            qf[hf][kt] = *(const bfrag*)(Qp + (size_t)(hf * 16 + l15) * HD + kt * 32 + quad * 8);

    // j-invariant LDS read offsets (within a stage)
    int kAddr[2];
#pragma unroll
    for (int kt = 0; kt < 2; ++kt)
        kAddr[kt] = l15 * 128 + (((kt * 4 + quad) ^ (l15 & 7)) * 16);
    int vAddr[2][2];
#pragma unroll
    for (int a = 0; a < 2; ++a)
#pragma unroll
        for (int g = 0; g < 2; ++g)
            vAddr[a][g] = 16384 + l15 * 256 + (((a * 8 + g * 4 + quad) ^ l15) * 16);

    const f32x4 z4 = (f32x4)0.0f;
    const bfrag ones8 = {0x3F80, 0x3F80, 0x3F80, 0x3F80,
                         0x3F80, 0x3F80, 0x3F80, 0x3F80};  // bf16 1.0 x8

    f32x4 oacc[2][4], ol[2];
#pragma unroll
    for (int hf = 0; hf < 2; ++hf) {
        ol[hf] = z4;
#pragma unroll
        for (int dt = 0; dt < 4; ++dt) oacc[hf][dt] = z4;
    }

    // prologue: stage tile 0 into buffer 0, and the mask row into LDS @65536
#pragma unroll
    for (int i = 0; i < 4; ++i) {
        gload_lds16(kBase + ksrc[i], smem + wave * 4096 + i * 1024);
        gload_lds16(vBase + vsrc[i], smem + 16384 + wave * 4096 + i * 1024);
    }
#pragma unroll
    for (int i = 0; i < 2; ++i) {
        int ci = wave * 128 + i * 64 + lane;            // linear 16B chunks
        gload_lds16((const char*)(maskl + b * SS) + ci * 16,
                    smem + 65536 + wave * 2048 + i * 1024);
    }

    int mOff = 65536 + quad * 16;   // LDS byte offset of this lane's mask slice

    auto astep = [&](int CUR, int NXT, int jn, int pref) {
        __syncthreads();   // tile-j loads landed; prior compute done (buffer free)
        if (pref) {
#pragma unroll
            for (int i = 0; i < 4; ++i) {
                gload_lds16(kBase + (size_t)jn * 16384 + ksrc[i],
                            smem + NXT + wave * 4096 + i * 1024);
                gload_lds16(vBase + (size_t)jn * 256 + vsrc[i],
                            smem + NXT + 16384 + wave * 4096 + i * 1024);
            }
        }

        // S^T = K * Q^T + mask, two independent 64-key sub-tiles.
        // mask comes from LDS (lgkmcnt path) — no vmcnt wait in the loop body.
        f32x4 s0[2][4], s1[2][4];
        __builtin_amdgcn_s_setprio(1);
#pragma unroll
        for (int a = 0; a < 2; ++a) {
            f32x4 mvl[4];
#pragma unroll
            for (int ct = 0; ct < 4; ++ct)
                mvl[ct] = *(const f32x4*)(smem + mOff + a * 256 + ct * 64);
#pragma unroll
            for (int ct = 0; ct < 4; ++ct) {
                bfrag kf0 = *(const bfrag*)(smem + CUR + a * 8192 + kAddr[0] + ct * 2048);
                bfrag kf1 = *(const bfrag*)(smem + CUR + a * 8192 + kAddr[1] + ct * 2048);
                s0[a][ct] = __builtin_amdgcn_mfma_f32_16x16x32_bf16(kf0, qf[0][0], mvl[ct], 0, 0, 0);
                s0[a][ct] = __builtin_amdgcn_mfma_f32_16x16x32_bf16(kf1, qf[0][1], s0[a][ct], 0, 0, 0);
                s1[a][ct] = __builtin_amdgcn_mfma_f32_16x16x32_bf16(kf0, qf[1][0], mvl[ct], 0, 0, 0);
                s1[a][ct] = __builtin_amdgcn_mfma_f32_16x16x32_bf16(kf1, qf[1][1], s1[a][ct], 0, 0, 0);
            }
        }
        __builtin_amdgcn_s_setprio(0);
        mOff += 512;

        // softmax numerators: 64 exp + 32 pack per astep, packed directly into
        // K=32 A-frags: p[a][g] = concat(pf[2g], pf[2g+1]) (k-order matches V chunk)
        bfrag p0[2][2], p1[2][2];
#pragma unroll
        for (int a = 0; a < 2; ++a)
#pragma unroll
            for (int g = 0; g < 2; ++g) {
                union { uint32_t u[4]; bfrag v; } cvt;
                cvt.u[0] = pack_bf16(__builtin_amdgcn_exp2f(s0[a][2*g][0]),   __builtin_amdgcn_exp2f(s0[a][2*g][1]));
                cvt.u[1] = pack_bf16(__builtin_amdgcn_exp2f(s0[a][2*g][2]),   __builtin_amdgcn_exp2f(s0[a][2*g][3]));
                cvt.u[2] = pack_bf16(__builtin_amdgcn_exp2f(s0[a][2*g+1][0]), __builtin_amdgcn_exp2f(s0[a][2*g+1][1]));
                cvt.u[3] = pack_bf16(__builtin_amdgcn_exp2f(s0[a][2*g+1][2]), __builtin_amdgcn_exp2f(s0[a][2*g+1][3]));
                p0[a][g] = cvt.v;
                cvt.u[0] = pack_bf16(__builtin_amdgcn_exp2f(s1[a][2*g][0]),   __builtin_amdgcn_exp2f(s1[a][2*g][1]));
                cvt.u[1] = pack_bf16(__builtin_amdgcn_exp2f(s1[a][2*g][2]),   __builtin_amdgcn_exp2f(s1[a][2*g][3]));
                cvt.u[2] = pack_bf16(__builtin_amdgcn_exp2f(s1[a][2*g+1][0]), __builtin_amdgcn_exp2f(s1[a][2*g+1][1]));
                cvt.u[3] = pack_bf16(__builtin_amdgcn_exp2f(s1[a][2*g+1][2]), __builtin_amdgcn_exp2f(s1[a][2*g+1][3]));
                p1[a][g] = cvt.v;
            }

        // O += P*V : one b128 V read == K=32 B-operand, feeds both halves.
        // (a,g) outer, dt inner: same-accumulator MFMAs >= 8 instrs apart.
        __builtin_amdgcn_s_setprio(1);
#pragma unroll
        for (int a = 0; a < 2; ++a)
#pragma unroll
            for (int g = 0; g < 2; ++g) {
                bfrag vv[4];
#pragma unroll
                for (int dt = 0; dt < 4; ++dt)
                    vv[dt] = *(const bfrag*)(smem + CUR + vAddr[a][g] + dt * 4096);
#pragma unroll
                for (int dt = 0; dt < 4; ++dt) {
                    oacc[0][dt] = __builtin_amdgcn_mfma_f32_16x16x32_bf16(p0[a][g], vv[dt], oacc[0][dt], 0, 0, 0);
                    oacc[1][dt] = __builtin_amdgcn_mfma_f32_16x16x32_bf16(p1[a][g], vv[dt], oacc[1][dt], 0, 0, 0);
                }
                ol[0] = __builtin_amdgcn_mfma_f32_16x16x32_bf16(p0[a][g], ones8, ol[0], 0, 0, 0);
                ol[1] = __builtin_amdgcn_mfma_f32_16x16x32_bf16(p1[a][g], ones8, ol[1], 0, 0, 0);
            }
        __builtin_amdgcn_s_setprio(0);
    };

    for (int jj = 0; jj < 8; ++jj) {
        astep(0,     32768, 2 * jj + 1, 1);
        astep(32768, 0,     2 * jj + 2, jj < 7);
    }

    // epilogue: out[b][qrow][h*64+d] fp32; O rows = quad*4+r, cols = l15 (+16*dt)
#pragma unroll
    for (int hf = 0; hf < 2; ++hf) {
#pragma unroll
        for (int r = 0; r < 4; ++r) {
            float linv = 1.0f / ol[hf][r];
            int qrow = qBase + hf * 16 + quad * 4 + r;
#pragma unroll
            for (int dt = 0; dt < 4; ++dt)
                out[((size_t)(b * SS + qrow)) * HH + h * 64 + dt * 16 + l15] =
                    oacc[hf][dt][r] * linv;
        }
    }
}

extern "C" void kernel_launch(void* const* d_in, const int* in_sizes, int n_in,
                              void* d_out, int out_size, void* d_ws, size_t ws_size,
                              hipStream_t stream) {
    const float* hs   = (const float*)d_in[0];
    const float* mask = (const float*)d_in[1];
    const float* Wq   = (const float*)d_in[2];
    const float* bq   = (const float*)d_in[3];
    const float* Wk   = (const float*)d_in[4];
    const float* bk   = (const float*)d_in[5];
    const float* Wv   = (const float*)d_in[6];
    const float* bv   = (const float*)d_in[7];
    float* out = (float*)d_out;

    char* ws = (char*)d_ws;
    short* Xb    = (short*)(ws);                      // [4096][1024] bf16, 8 MiB
    short* Wcat  = (short*)(ws + (8ull  << 20));      // [3072][1024] bf16, 6 MiB (Wq|Wk|Wv)
    short* Qb    = (short*)(ws + (14ull << 20));      // [bh][s][d] 8 MiB (pre-scaled)
    short* Kb    = (short*)(ws + (22ull << 20));      // [bh][s][d] 8 MiB
    short* Vb    = (short*)(ws + (30ull << 20));      // [bh][d][s-permuted] 8 MiB
    float* maskl = (float*)(ws + (38ull << 20));      // [B][S] fp32, 16 KiB

    cvt_all<<<7172, 256, 0, stream>>>(hs, Wq, Wk, Wv, mask, Xb, Wcat, maskl);

    qkv_gemm<<<dim3(24, 32), 256, 0, stream>>>(Xb, Wcat, bq, bk, bv, Qb, Kb, Vb);

    attn_kernel<<<512, 256, 0, stream>>>(Qb, Kb, Vb, maskl, out);
}